// Round 5
// baseline (608.618 us; speedup 1.0000x reference)
//
#include <hip/hip_runtime.h>
#include <math.h>

// FlowLevel: DIM=2, half=1 -> per-layer coupling depends on scalar v = z_b.
// t(v) and u(v) (pre-sigmoid) are piecewise-LINEAR in v (ReLU MLP).
// Tabulate (t, dt/dv, u, du/dv) per node; reconstruct with two tangent
// lines (exact for <=1 kink per cell). sigmoid/log-sigmoid computed exactly
// in the apply kernel from reconstructed u.
//
// Build kernel v4: designed FOR the compiler's 64-VGPR preference.
//  - 32-node tile -> LDS 19.97 KB -> 8 blocks/CU (64-reg occupancy pays off).
//  - value pass then deriv pass, 16 accumulators each; ReLU gates carried
//    A->B in one uint32; each pass writes its half of the table entry.
//  - phase-2 h-reads are wave-broadcast (2 addresses/wave, conflict-free).
//  - #pragma unroll 1 on j-loops: hide latency with 8-wave TLP, not regs.

constexpr int kDepth = 10;
constexpr int kWidth = 128;
constexpr float kVMin = -24.0f;
constexpr float kVMax =  24.0f;

__global__ __launch_bounds__(256) void build_tables_kernel(
    const float* __restrict__ an_scale,
    const float* __restrict__ conv_w,
    const float* __restrict__ fc1_w, const float* __restrict__ fc1_b,
    const float* __restrict__ an1_scale, const float* __restrict__ an1_bias,
    const float* __restrict__ fc2_w, const float* __restrict__ fc2_b,
    const float* __restrict__ an2_scale, const float* __restrict__ an2_bias,
    const float* __restrict__ fc3_w, const float* __restrict__ fc3_b,
    const float* __restrict__ lsf,
    int tabN,
    float4* __restrict__ tab, float* __restrict__ extra)
{
  __shared__ float4 sW1s[32];          // w1/s1 as 32 float4 chunks (512 B)
  __shared__ float4 sBb[32];           // (b1-z1)/s1 (512 B)
  __shared__ float  sH[32][132];       // h1 tile, padded stride (16.9 KB)
  __shared__ float  sB2z[128], sS2i[128], sW3a[128], sW3b[128];  // 2 KB

  const int bpl   = tabN >> 5;                 // blocks per layer
  const int layer = blockIdx.x / bpl;
  const int node0 = (blockIdx.x % bpl) * 32;
  const int tid   = threadIdx.x;
  const float dv  = (kVMax - kVMin) / (float)(tabN - 1);

  // ---- phase 0: layer-uniform constants into LDS ----
  if (tid < 128) {
    const int j = tid;
    const float inv1 = 1.0f / an1_scale[layer*kWidth + j];
    ((float*)sW1s)[j] = fc1_w[layer*kWidth + j] * inv1;
    ((float*)sBb)[j]  = (fc1_b[layer*kWidth + j] - an1_bias[layer*kWidth + j]) * inv1;
    sB2z[j] = fc2_b[layer*kWidth + j] - an2_bias[layer*kWidth + j];
    sS2i[j] = 1.0f / an2_scale[layer*kWidth + j];
    sW3a[j] = fc3_w[layer*2*kWidth + j];
    sW3b[j] = fc3_w[layer*2*kWidth + kWidth + j];
  }
  __syncthreads();

  // ---- phase 1: fill h1 tile (32 nodes x 128 j) ----
  {
    const int node = tid & 31;
    const int q0   = (tid >> 5) * 4;       // float4 chunk base
    const float v = kVMin + dv * (float)(node0 + node);
#pragma unroll
    for (int c = 0; c < 4; ++c) {
      float4 w = sW1s[q0 + c];
      float4 b = sBb[q0 + c];
      float4 h;
      h.x = fmaxf(fmaf(v, w.x, b.x), 0.0f);
      h.y = fmaxf(fmaf(v, w.y, b.y), 0.0f);
      h.z = fmaxf(fmaf(v, w.z, b.z), 0.0f);
      h.w = fmaxf(fmaf(v, w.w, b.w), 0.0f);
      *(float4*)&sH[node][(q0 + c) * 4] = h;
    }
  }
  __syncthreads();

  const int kg = tid & 31;   // k-group: k = kg*4 + kk
  const int ng = tid >> 5;   // node-group: node = ng*4 + nn
  const float4* __restrict__ w2p =
      (const float4*)fc2_w + (size_t)layer * 4096 + (size_t)kg * 128;
  const size_t tabBase = (size_t)layer * tabN + node0 + ng * 4;

  unsigned gates = 0u;

  // ================= pass A: value dots =================
  {
    float a[4][4];
    float o0[4] = {0,0,0,0}, o1[4] = {0,0,0,0};
#pragma unroll
    for (int nn = 0; nn < 4; ++nn)
#pragma unroll
      for (int kk = 0; kk < 4; ++kk) a[nn][kk] = 0.0f;

#pragma unroll 1
    for (int jc = 0; jc < 32; ++jc) {
      float4 wk0 = w2p[jc];
      float4 wk1 = w2p[jc + 32];
      float4 wk2 = w2p[jc + 64];
      float4 wk3 = w2p[jc + 96];
#pragma unroll
      for (int nn = 0; nn < 4; ++nn) {
        float4 h = *(const float4*)&sH[ng*4 + nn][jc * 4];   // wave-broadcast
        a[nn][0] = fmaf(h.w, wk0.w, fmaf(h.z, wk0.z, fmaf(h.y, wk0.y, fmaf(h.x, wk0.x, a[nn][0]))));
        a[nn][1] = fmaf(h.w, wk1.w, fmaf(h.z, wk1.z, fmaf(h.y, wk1.y, fmaf(h.x, wk1.x, a[nn][1]))));
        a[nn][2] = fmaf(h.w, wk2.w, fmaf(h.z, wk2.z, fmaf(h.y, wk2.y, fmaf(h.x, wk2.x, a[nn][2]))));
        a[nn][3] = fmaf(h.w, wk3.w, fmaf(h.z, wk3.z, fmaf(h.y, wk3.y, fmaf(h.x, wk3.x, a[nn][3]))));
      }
    }

    // epilogue A: relu gate + fc3 value partials
#pragma unroll
    for (int kk = 0; kk < 4; ++kk) {
      const int k = kg*4 + kk;
      const float bz = sB2z[k], si = sS2i[k], wa = sW3a[k], wb = sW3b[k];
#pragma unroll
      for (int nn = 0; nn < 4; ++nn) {
        float pre = (a[nn][kk] + bz) * si;
        bool  on  = pre > 0.0f;
        float h2  = on ? pre : 0.0f;
        gates |= (on ? 1u : 0u) << (nn*4 + kk);
        o0[nn] = fmaf(h2, wa, o0[nn]);
        o1[nn] = fmaf(h2, wb, o1[nn]);
      }
    }
#pragma unroll
    for (int off = 16; off >= 1; off >>= 1) {
#pragma unroll
      for (int nn = 0; nn < 4; ++nn) {
        o0[nn] += __shfl_xor(o0[nn], off);
        o1[nn] += __shfl_xor(o1[nn], off);
      }
    }
    if (kg == 0) {
      const float E0 = expf(lsf[layer*2 + 0]);
      const float E1 = expf(lsf[layer*2 + 1]);
      const float b30 = fc3_b[layer*2 + 0];
      const float b31 = fc3_b[layer*2 + 1];
#pragma unroll
      for (int nn = 0; nn < 4; ++nn) {
        float* p = (float*)&tab[tabBase + nn];
        p[0] = (o0[nn] + b30) * E0;   // t
        p[2] = (o1[nn] + b31) * E1;   // u
      }
    }
  }

  // ================= pass B: derivative dots =================
  {
    float c[4][4];
    float p0[4] = {0,0,0,0}, p1[4] = {0,0,0,0};
#pragma unroll
    for (int nn = 0; nn < 4; ++nn)
#pragma unroll
      for (int kk = 0; kk < 4; ++kk) c[nn][kk] = 0.0f;

#pragma unroll 1
    for (int jc = 0; jc < 32; ++jc) {
      float4 wk0 = w2p[jc];
      float4 wk1 = w2p[jc + 32];
      float4 wk2 = w2p[jc + 64];
      float4 wk3 = w2p[jc + 96];
      float4 wg  = sW1s[jc];                                  // broadcast
#pragma unroll
      for (int nn = 0; nn < 4; ++nn) {
        float4 h = *(const float4*)&sH[ng*4 + nn][jc * 4];    // wave-broadcast
        float dx = (h.x > 0.0f) ? wg.x : 0.0f;
        float dy = (h.y > 0.0f) ? wg.y : 0.0f;
        float dz = (h.z > 0.0f) ? wg.z : 0.0f;
        float dw = (h.w > 0.0f) ? wg.w : 0.0f;
        c[nn][0] = fmaf(dw, wk0.w, fmaf(dz, wk0.z, fmaf(dy, wk0.y, fmaf(dx, wk0.x, c[nn][0]))));
        c[nn][1] = fmaf(dw, wk1.w, fmaf(dz, wk1.z, fmaf(dy, wk1.y, fmaf(dx, wk1.x, c[nn][1]))));
        c[nn][2] = fmaf(dw, wk2.w, fmaf(dz, wk2.z, fmaf(dy, wk2.y, fmaf(dx, wk2.x, c[nn][2]))));
        c[nn][3] = fmaf(dw, wk3.w, fmaf(dz, wk3.z, fmaf(dy, wk3.y, fmaf(dx, wk3.x, c[nn][3]))));
      }
    }

    // epilogue B: gated deriv + fc3 deriv partials
#pragma unroll
    for (int kk = 0; kk < 4; ++kk) {
      const int k = kg*4 + kk;
      const float si = sS2i[k], wa = sW3a[k], wb = sW3b[k];
#pragma unroll
      for (int nn = 0; nn < 4; ++nn) {
        float dpre = c[nn][kk] * si;
        float dh2  = ((gates >> (nn*4 + kk)) & 1u) ? dpre : 0.0f;
        p0[nn] = fmaf(dh2, wa, p0[nn]);
        p1[nn] = fmaf(dh2, wb, p1[nn]);
      }
    }
#pragma unroll
    for (int off = 16; off >= 1; off >>= 1) {
#pragma unroll
      for (int nn = 0; nn < 4; ++nn) {
        p0[nn] += __shfl_xor(p0[nn], off);
        p1[nn] += __shfl_xor(p1[nn], off);
      }
    }
    if (kg == 0) {
      const float E0 = expf(lsf[layer*2 + 0]);
      const float E1 = expf(lsf[layer*2 + 1]);
#pragma unroll
      for (int nn = 0; nn < 4; ++nn) {
        float* p = (float*)&tab[tabBase + nn];
        p[1] = p0[nn] * E0;   // dt
        p[3] = p1[nn] * E1;   // du
      }
    }
  }

  // sample-independent logdet constant
  if (blockIdx.x == 0 && tid == 0) {
    float cst = 0.0f;
    for (int i = 0; i < kDepth; ++i) {
      cst -= logf(fabsf(an_scale[i*2+0]));
      cst -= logf(fabsf(an_scale[i*2+1]));
      const float* cw = conv_w + i * 4;
      float det = cw[0]*cw[3] - cw[1]*cw[2];
      cst += logf(fabsf(det));   // slogdet(conv)[1]
    }
    extra[0] = cst;
  }
}

// ---------------- main: per-sample 10-layer loop with two-line reconstruction ----------------
__global__ __launch_bounds__(256) void flow_apply_kernel(
    const float* __restrict__ x,
    const float* __restrict__ an_scale, const float* __restrict__ an_bias,
    const float* __restrict__ conv_w,
    const float4* __restrict__ tab, const float* __restrict__ extra,
    int tabN,
    float* __restrict__ out_z, float* __restrict__ out_ld, int n)
{
  int idx = blockIdx.x * blockDim.x + threadIdx.x;
  if (idx >= n) return;

  float2 z = reinterpret_cast<const float2*>(x)[idx];
  float ld = extra[0];
  const float dv = (kVMax - kVMin) / (float)(tabN - 1);
  const float inv_dv = (float)(tabN - 1) / (kVMax - kVMin);

#pragma unroll
  for (int i = 0; i < kDepth; ++i) {
    // actnorm
    float za = (z.x - an_bias[i*2+0]) / an_scale[i*2+0];
    float zb = (z.y - an_bias[i*2+1]) / an_scale[i*2+1];
    // 1x1 conv (2x2): z' = W z
    const float* cw = conv_w + i*4;
    float na = fmaf(cw[0], za, cw[1]*zb);
    float nb = fmaf(cw[2], za, cw[3]*zb);
    // table cell
    float xq = (nb - kVMin) * inv_dv;
    int qi = (int)floorf(xq);
    qi = qi < 0 ? 0 : (qi > tabN-2 ? tabN-2 : qi);
    float v0 = fmaf((float)qi, dv, kVMin);
    float v1 = v0 + dv;
    float4 e0 = tab[(size_t)i*tabN + qi];
    float4 e1 = tab[(size_t)i*tabN + qi + 1];
    // two-tangent-line reconstruction (exact for <=1 kink per cell)
    float tL = fmaf(nb - v0, e0.y, e0.x);
    float tR = fmaf(nb - v1, e1.y, e1.x);
    float tt = (e1.y >= e0.y) ? fmaxf(tL, tR) : fminf(tL, tR);
    float uL = fmaf(nb - v0, e0.w, e0.z);
    float uR = fmaf(nb - v1, e1.w, e1.z);
    float uu = (e1.w >= e0.w) ? fmaxf(uL, uR) : fminf(uL, uR);
    // exact sigmoid / log-sigmoid of arg = u + 2
    float arg = uu + 2.0f;
    float e = expf(-arg);
    float s = 1.0f / (1.0f + e);
    float lsv = -logf(1.0f + e);
    // coupling
    z.x = fmaf(s, na, tt);
    z.y = nb;
    ld += lsv;
  }

  reinterpret_cast<float2*>(out_z)[idx] = z;
  out_ld[idx] = ld;
}

extern "C" void kernel_launch(void* const* d_in, const int* in_sizes, int n_in,
                              void* d_out, int out_size, void* d_ws, size_t ws_size,
                              hipStream_t stream) {
  const float* x         = (const float*)d_in[0];
  const float* an_scale  = (const float*)d_in[1];
  const float* an_bias   = (const float*)d_in[2];
  const float* conv_w    = (const float*)d_in[3];
  const float* fc1_w     = (const float*)d_in[4];
  const float* fc1_b     = (const float*)d_in[5];
  const float* an1_scale = (const float*)d_in[6];
  const float* an1_bias  = (const float*)d_in[7];
  const float* fc2_w     = (const float*)d_in[8];
  const float* fc2_b     = (const float*)d_in[9];
  const float* an2_scale = (const float*)d_in[10];
  const float* an2_bias  = (const float*)d_in[11];
  const float* fc3_w     = (const float*)d_in[12];
  const float* fc3_b     = (const float*)d_in[13];
  const float* lsf       = (const float*)d_in[14];

  const int n = in_sizes[0] / 2;

  // workspace layout: [extra: 16 floats][table: float4 x kDepth x tabN]
  int tabN = 16384;
  while (tabN > 2048 &&
         (size_t)64 + (size_t)kDepth * tabN * sizeof(float4) > ws_size) {
    tabN >>= 1;
  }
  float* extra = (float*)d_ws;
  float4* tab  = (float4*)((char*)d_ws + 64);

  build_tables_kernel<<<kDepth * (tabN / 32), 256, 0, stream>>>(
      an_scale, conv_w, fc1_w, fc1_b, an1_scale, an1_bias,
      fc2_w, fc2_b, an2_scale, an2_bias, fc3_w, fc3_b, lsf, tabN, tab, extra);

  float* out_z  = (float*)d_out;
  float* out_ld = out_z + (size_t)2 * n;
  flow_apply_kernel<<<(n + 255) / 256, 256, 0, stream>>>(
      x, an_scale, an_bias, conv_w, tab, extra, tabN, out_z, out_ld, n);
}

// Round 6
// 237.663 us; speedup vs baseline: 2.5609x; 2.5609x over previous
//
#include <hip/hip_runtime.h>
#include <math.h>

// FlowLevel: DIM=2, half=1 -> per-layer coupling depends on scalar v = z_b.
// t(v) and u(v) (pre-sigmoid) are piecewise-LINEAR in v (ReLU MLP).
// Tabulate (t, dt/dv, u, du/dv) per node; reconstruct with two tangent
// lines (exact for <=1 kink per cell). sigmoid/log-sigmoid computed exactly
// in the apply kernel from reconstructed u.
//
// Build kernel v5: kill the divergent global weight loads (v2-v4's stall).
//  - fc2_w consumed from LDS in 4 slabs of 32 k-rows; each slab loaded
//    COALESCED by the whole block (4 float4/thread), then read broadcast.
//  - thread (kg,ng) = 4 nodes x 2 k (k = kg, kg+16 -> 2-way banks = free),
//    value+deriv fused: 16 accumulators, ~70 live VGPRs.
//  - LDS 52.5 KB -> 3 blocks/CU; __launch_bounds__(256,3) so the compiler
//    allocates registers for 3 waves/EU instead of chasing 8.

constexpr int kDepth = 10;
constexpr int kWidth = 128;
constexpr float kVMin = -24.0f;
constexpr float kVMax =  24.0f;

__global__ __launch_bounds__(256, 3) void build_tables_kernel(
    const float* __restrict__ an_scale,
    const float* __restrict__ conv_w,
    const float* __restrict__ fc1_w, const float* __restrict__ fc1_b,
    const float* __restrict__ an1_scale, const float* __restrict__ an1_bias,
    const float* __restrict__ fc2_w, const float* __restrict__ fc2_b,
    const float* __restrict__ an2_scale, const float* __restrict__ an2_bias,
    const float* __restrict__ fc3_w, const float* __restrict__ fc3_b,
    const float* __restrict__ lsf,
    int tabN,
    float4* __restrict__ tab, float* __restrict__ extra)
{
  __shared__ float4 sW1s[32];            // w1/s1 as float4 chunks (512 B)
  __shared__ float4 sBb[32];             // (b1-z1)/s1 (512 B)
  __shared__ float  sH[64 * 132];        // h1 tile, stride 132 (33.8 KB)
  __shared__ float  sW2[32 * 132];       // weight slab, stride 132 (16.9 KB)
  __shared__ float  sB2z[128], sS2i[128], sW3a[128], sW3b[128];  // 2 KB

  const int bpl   = tabN >> 6;                 // blocks per layer
  const int layer = blockIdx.x / bpl;
  const int node0 = (blockIdx.x % bpl) * 64;
  const int tid   = threadIdx.x;
  const float dv  = (kVMax - kVMin) / (float)(tabN - 1);

  // ---- phase 0: layer-uniform constants into LDS ----
  if (tid < 128) {
    const int j = tid;
    const float inv1 = 1.0f / an1_scale[layer*kWidth + j];
    ((float*)sW1s)[j] = fc1_w[layer*kWidth + j] * inv1;
    ((float*)sBb)[j]  = (fc1_b[layer*kWidth + j] - an1_bias[layer*kWidth + j]) * inv1;
    sB2z[j] = fc2_b[layer*kWidth + j] - an2_bias[layer*kWidth + j];
    sS2i[j] = 1.0f / an2_scale[layer*kWidth + j];
    sW3a[j] = fc3_w[layer*2*kWidth + j];
    sW3b[j] = fc3_w[layer*2*kWidth + kWidth + j];
  }
  __syncthreads();

  // ---- phase 1: fill h1 tile (64 nodes x 128 j) ----
  {
    const int node = tid & 63;
    const int cq0  = (tid >> 6) * 8;       // float4 chunk base 0,8,16,24
    const float v = kVMin + dv * (float)(node0 + node);
#pragma unroll
    for (int c = 0; c < 8; ++c) {
      float4 w = sW1s[cq0 + c];
      float4 b = sBb[cq0 + c];
      float4 h;
      h.x = fmaxf(fmaf(v, w.x, b.x), 0.0f);
      h.y = fmaxf(fmaf(v, w.y, b.y), 0.0f);
      h.z = fmaxf(fmaf(v, w.z, b.z), 0.0f);
      h.w = fmaxf(fmaf(v, w.w, b.w), 0.0f);
      *(float4*)&sH[node * 132 + (cq0 + c) * 4] = h;
    }
  }

  const int kg = tid & 15;   // k within slab: k = kg and kg+16
  const int ng = tid >> 4;   // node group: nodes ng*4 .. ng*4+3
  const float4* __restrict__ w2g =
      (const float4*)fc2_w + (size_t)layer * 4096;   // 1024 float4 per slab

  float o0[4] = {0,0,0,0}, o1[4] = {0,0,0,0};
  float p0[4] = {0,0,0,0}, p1[4] = {0,0,0,0};

#pragma unroll 1
  for (int slab = 0; slab < 4; ++slab) {
    // ---- stage 32 k-rows of fc2_w into LDS, coalesced ----
    __syncthreads();
#pragma unroll
    for (int i = 0; i < 4; ++i) {
      const int fi  = tid + 256 * i;          // float4 index in slab
      float4 w = w2g[slab * 1024 + fi];
      const int row = fi >> 5, col = fi & 31;
      *(float4*)&sW2[row * 132 + col * 4] = w;
    }
    __syncthreads();

    // ---- fused value+deriv dots for this slab ----
    float a[4][2], c[4][2];
#pragma unroll
    for (int nn = 0; nn < 4; ++nn) {
      a[nn][0] = 0.0f; a[nn][1] = 0.0f;
      c[nn][0] = 0.0f; c[nn][1] = 0.0f;
    }

#pragma unroll 2
    for (int jc = 0; jc < 32; ++jc) {
      float4 w0 = *(const float4*)&sW2[kg * 132 + jc * 4];         // k = kg
      float4 w1 = *(const float4*)&sW2[(kg + 16) * 132 + jc * 4];  // k = kg+16
      float4 wg = sW1s[jc];                                        // broadcast
#pragma unroll
      for (int nn = 0; nn < 4; ++nn) {
        float4 h = *(const float4*)&sH[(ng * 4 + nn) * 132 + jc * 4]; // 2-way
        float dx = (h.x > 0.0f) ? wg.x : 0.0f;
        float dy = (h.y > 0.0f) ? wg.y : 0.0f;
        float dz = (h.z > 0.0f) ? wg.z : 0.0f;
        float dw = (h.w > 0.0f) ? wg.w : 0.0f;
        a[nn][0] = fmaf(h.w, w0.w, fmaf(h.z, w0.z, fmaf(h.y, w0.y, fmaf(h.x, w0.x, a[nn][0]))));
        a[nn][1] = fmaf(h.w, w1.w, fmaf(h.z, w1.z, fmaf(h.y, w1.y, fmaf(h.x, w1.x, a[nn][1]))));
        c[nn][0] = fmaf(dw, w0.w, fmaf(dz, w0.z, fmaf(dy, w0.y, fmaf(dx, w0.x, c[nn][0]))));
        c[nn][1] = fmaf(dw, w1.w, fmaf(dz, w1.z, fmaf(dy, w1.y, fmaf(dx, w1.x, c[nn][1]))));
      }
    }

    // ---- epilogue for this slab: relu + fc3 partials ----
#pragma unroll
    for (int kk = 0; kk < 2; ++kk) {
      const int k = slab * 32 + kg + 16 * kk;
      const float bz = sB2z[k], si = sS2i[k], wa = sW3a[k], wb = sW3b[k];
#pragma unroll
      for (int nn = 0; nn < 4; ++nn) {
        float pre  = (a[nn][kk] + bz) * si;
        float dpre = c[nn][kk] * si;
        bool  on   = pre > 0.0f;
        float h2   = on ? pre  : 0.0f;
        float dh2  = on ? dpre : 0.0f;
        o0[nn] = fmaf(h2,  wa, o0[nn]);
        p0[nn] = fmaf(dh2, wa, p0[nn]);
        o1[nn] = fmaf(h2,  wb, o1[nn]);
        p1[nn] = fmaf(dh2, wb, p1[nn]);
      }
    }
  }

  // ---- reduce over the 16 kg lanes (xor bits 0..3 only), write ----
#pragma unroll
  for (int off = 8; off >= 1; off >>= 1) {
#pragma unroll
    for (int nn = 0; nn < 4; ++nn) {
      o0[nn] += __shfl_xor(o0[nn], off);
      o1[nn] += __shfl_xor(o1[nn], off);
      p0[nn] += __shfl_xor(p0[nn], off);
      p1[nn] += __shfl_xor(p1[nn], off);
    }
  }
  if (kg == 0) {
    const float E0 = expf(lsf[layer*2 + 0]);
    const float E1 = expf(lsf[layer*2 + 1]);
    const float b30 = fc3_b[layer*2 + 0];
    const float b31 = fc3_b[layer*2 + 1];
    const size_t tabBase = (size_t)layer * tabN + node0 + ng * 4;
#pragma unroll
    for (int nn = 0; nn < 4; ++nn) {
      tab[tabBase + nn] =
          make_float4((o0[nn] + b30) * E0, p0[nn] * E0,
                      (o1[nn] + b31) * E1, p1[nn] * E1);
    }
  }

  // sample-independent logdet constant
  if (blockIdx.x == 0 && tid == 0) {
    float cst = 0.0f;
    for (int i = 0; i < kDepth; ++i) {
      cst -= logf(fabsf(an_scale[i*2+0]));
      cst -= logf(fabsf(an_scale[i*2+1]));
      const float* cw = conv_w + i * 4;
      float det = cw[0]*cw[3] - cw[1]*cw[2];
      cst += logf(fabsf(det));   // slogdet(conv)[1]
    }
    extra[0] = cst;
  }
}

// ---------------- main: per-sample 10-layer loop with two-line reconstruction ----------------
__global__ __launch_bounds__(256) void flow_apply_kernel(
    const float* __restrict__ x,
    const float* __restrict__ an_scale, const float* __restrict__ an_bias,
    const float* __restrict__ conv_w,
    const float4* __restrict__ tab, const float* __restrict__ extra,
    int tabN,
    float* __restrict__ out_z, float* __restrict__ out_ld, int n)
{
  int idx = blockIdx.x * blockDim.x + threadIdx.x;
  if (idx >= n) return;

  float2 z = reinterpret_cast<const float2*>(x)[idx];
  float ld = extra[0];
  const float dv = (kVMax - kVMin) / (float)(tabN - 1);
  const float inv_dv = (float)(tabN - 1) / (kVMax - kVMin);

#pragma unroll
  for (int i = 0; i < kDepth; ++i) {
    // actnorm
    float za = (z.x - an_bias[i*2+0]) / an_scale[i*2+0];
    float zb = (z.y - an_bias[i*2+1]) / an_scale[i*2+1];
    // 1x1 conv (2x2): z' = W z
    const float* cw = conv_w + i*4;
    float na = fmaf(cw[0], za, cw[1]*zb);
    float nb = fmaf(cw[2], za, cw[3]*zb);
    // table cell
    float xq = (nb - kVMin) * inv_dv;
    int qi = (int)floorf(xq);
    qi = qi < 0 ? 0 : (qi > tabN-2 ? tabN-2 : qi);
    float v0 = fmaf((float)qi, dv, kVMin);
    float v1 = v0 + dv;
    float4 e0 = tab[(size_t)i*tabN + qi];
    float4 e1 = tab[(size_t)i*tabN + qi + 1];
    // two-tangent-line reconstruction (exact for <=1 kink per cell)
    float tL = fmaf(nb - v0, e0.y, e0.x);
    float tR = fmaf(nb - v1, e1.y, e1.x);
    float tt = (e1.y >= e0.y) ? fmaxf(tL, tR) : fminf(tL, tR);
    float uL = fmaf(nb - v0, e0.w, e0.z);
    float uR = fmaf(nb - v1, e1.w, e1.z);
    float uu = (e1.w >= e0.w) ? fmaxf(uL, uR) : fminf(uL, uR);
    // exact sigmoid / log-sigmoid of arg = u + 2
    float arg = uu + 2.0f;
    float e = expf(-arg);
    float s = 1.0f / (1.0f + e);
    float lsv = -logf(1.0f + e);
    // coupling
    z.x = fmaf(s, na, tt);
    z.y = nb;
    ld += lsv;
  }

  reinterpret_cast<float2*>(out_z)[idx] = z;
  out_ld[idx] = ld;
}

extern "C" void kernel_launch(void* const* d_in, const int* in_sizes, int n_in,
                              void* d_out, int out_size, void* d_ws, size_t ws_size,
                              hipStream_t stream) {
  const float* x         = (const float*)d_in[0];
  const float* an_scale  = (const float*)d_in[1];
  const float* an_bias   = (const float*)d_in[2];
  const float* conv_w    = (const float*)d_in[3];
  const float* fc1_w     = (const float*)d_in[4];
  const float* fc1_b     = (const float*)d_in[5];
  const float* an1_scale = (const float*)d_in[6];
  const float* an1_bias  = (const float*)d_in[7];
  const float* fc2_w     = (const float*)d_in[8];
  const float* fc2_b     = (const float*)d_in[9];
  const float* an2_scale = (const float*)d_in[10];
  const float* an2_bias  = (const float*)d_in[11];
  const float* fc3_w     = (const float*)d_in[12];
  const float* fc3_b     = (const float*)d_in[13];
  const float* lsf       = (const float*)d_in[14];

  const int n = in_sizes[0] / 2;

  // workspace layout: [extra: 16 floats][table: float4 x kDepth x tabN]
  int tabN = 16384;
  while (tabN > 2048 &&
         (size_t)64 + (size_t)kDepth * tabN * sizeof(float4) > ws_size) {
    tabN >>= 1;
  }
  float* extra = (float*)d_ws;
  float4* tab  = (float4*)((char*)d_ws + 64);

  build_tables_kernel<<<kDepth * (tabN / 64), 256, 0, stream>>>(
      an_scale, conv_w, fc1_w, fc1_b, an1_scale, an1_bias,
      fc2_w, fc2_b, an2_scale, an2_bias, fc3_w, fc3_b, lsf, tabN, tab, extra);

  float* out_z  = (float*)d_out;
  float* out_ld = out_z + (size_t)2 * n;
  flow_apply_kernel<<<(n + 255) / 256, 256, 0, stream>>>(
      x, an_scale, an_bias, conv_w, tab, extra, tabN, out_z, out_ld, n);
}